// Round 2
// baseline (1070.969 us; speedup 1.0000x reference)
//
#include <hip/hip_runtime.h>
#include <hip/hip_bf16.h>

#define DEV static __device__ __forceinline__

constexpr int B = 4, S = 2048, H = 8, D = 128, FH = 512;
constexpr int M = B * S;   // 8192

DEV float sigmoidf_(float x) { return 1.0f / (1.0f + __expf(-x)); }

// ---------------- K1: exclusive prefix sum along S ----------------
__global__ void k_prefix(const float* __restrict__ x, float* __restrict__ P) {
  int bh = blockIdx.x;            // b*H + h
  int b = bh / H, h = bh % H;
  int d = threadIdx.x;            // 0..127
  float acc = 0.0f;
  size_t base = ((size_t)b * S * H + h) * D + d;
  for (int s = 0; s < S; ++s) {
    size_t idx = base + (size_t)s * H * D;
    P[idx] = acc;
    acc += x[idx];
  }
}

// ---------------- block stats helper (mean/var over n elems) ----------------
DEV void block_stats(float lsum, float lss, int n, float& mean, float& var) {
  #pragma unroll
  for (int o = 32; o > 0; o >>= 1) {
    lsum += __shfl_down(lsum, o);
    lss  += __shfl_down(lss, o);
  }
  __shared__ float wsum[4], wss[4];
  int wid = threadIdx.x >> 6;
  int nw = blockDim.x >> 6;
  if ((threadIdx.x & 63) == 0) { wsum[wid] = lsum; wss[wid] = lss; }
  __syncthreads();
  float s = 0.0f, q = 0.0f;
  for (int i = 0; i < nw; ++i) { s += wsum[i]; q += wss[i]; }
  mean = s / n;
  var = q / n - mean * mean;
}

// ---------------- K2: LN over (H,D)=1024 in-place on P -> csum ----------------
__global__ __launch_bounds__(256) void k_csum_ln(float* __restrict__ P,
                                                 const float* __restrict__ g,
                                                 const float* __restrict__ bb) {
  size_t m = blockIdx.x;
  float* row = P + m * (H * D);
  int t = threadIdx.x;
  float4 v = ((const float4*)row)[t];
  float lsum = v.x + v.y + v.z + v.w;
  float lss = v.x * v.x + v.y * v.y + v.z * v.z + v.w * v.w;
  float mean, var;
  block_stats(lsum, lss, H * D, mean, var);
  float rs = rsqrtf(var + 1e-6f);
  float4 gv = ((const float4*)g)[t];
  float4 bv = ((const float4*)bb)[t];
  float4 o;
  o.x = (v.x - mean) * rs * gv.x + bv.x;
  o.y = (v.y - mean) * rs * gv.y + bv.y;
  o.z = (v.z - mean) * rs * gv.z + bv.z;
  o.w = (v.w - mean) * rs * gv.w + bv.w;
  ((float4*)row)[t] = o;
}

// ---------------- generic tiled fp32 GEMM ----------------
// A sources: AMODE 0/2 -> two fp32 halves [pa0 | pa1], each row-stride D per (m,h)
//            AMODE 1   -> bf16 A (hid), K=FH
// EPI: 0 plain fp32 +bias; 1 bf16 store +bias; 2 fused i=ig*(acc+bias) into ifg slot
template <int N, int K, int AMODE, int EPI>
__global__ __launch_bounds__(256) void k_gemm(
    const float* __restrict__ pa0, const float* __restrict__ pa1,
    const __hip_bfloat16* __restrict__ pab,
    const float* __restrict__ Wt, const float* __restrict__ bias,
    float* __restrict__ out_f, __hip_bfloat16* __restrict__ out_b,
    float* __restrict__ ifg) {
  constexpr int BM = 64, BN = 64, BK = 16;
  __shared__ float As[BK][BM + 1];
  __shared__ float Bs[BK][BN];
  int h = blockIdx.z;
  int m0 = blockIdx.y * BM;
  int n0 = blockIdx.x * BN;
  int tid = threadIdx.x;
  int tx = tid & 15, ty = tid >> 4;
  float acc[4][4] = {};
  for (int kt = 0; kt < K; kt += BK) {
    {
      int k = tid & 15, mm = tid >> 4;
      int kk = kt + k;
      #pragma unroll
      for (int r = 0; r < 4; ++r) {
        int mg = m0 + mm + r * 16;
        float v;
        if (AMODE == 1) {
          v = __bfloat162float(pab[((size_t)mg * H + h) * K + kk]);
        } else {
          v = (kk < D) ? pa0[((size_t)mg * H + h) * D + kk]
                       : pa1[((size_t)mg * H + h) * D + kk - D];
        }
        As[k][mm + r * 16] = v;
      }
    }
    {
      int n = tid & 63, kb = tid >> 6;
      #pragma unroll
      for (int r = 0; r < 4; ++r) {
        int k = kb + r * 4;
        Bs[k][n] = Wt[((size_t)h * K + kt + k) * N + n0 + n];
      }
    }
    __syncthreads();
    #pragma unroll
    for (int k = 0; k < BK; ++k) {
      float a[4], bv[4];
      #pragma unroll
      for (int i = 0; i < 4; ++i) a[i] = As[k][ty * 4 + i];
      #pragma unroll
      for (int j = 0; j < 4; ++j) bv[j] = Bs[k][tx * 4 + j];
      #pragma unroll
      for (int i = 0; i < 4; ++i)
        #pragma unroll
        for (int j = 0; j < 4; ++j) acc[i][j] += a[i] * bv[j];
    }
    __syncthreads();
  }
  #pragma unroll
  for (int i = 0; i < 4; ++i) {
    int mg = m0 + ty * 4 + i;
    size_t mh = (size_t)mg * H + h;
    #pragma unroll
    for (int j = 0; j < 4; ++j) {
      int o = n0 + tx * 4 + j;
      float v = acc[i][j] + bias[h * N + o];
      if (EPI == 0) {
        out_f[mh * N + o] = v;
      } else if (EPI == 1) {
        out_b[mh * N + o] = __float2bfloat16(v);
      } else {
        size_t idx = (mh * 2 + 0) * D + o;  // igate slot
        float ig = ifg[idx];
        ifg[idx] = ig * v;
      }
    }
  }
}

// ---------------- K5: LN over (H,2,D)=2048, then sigmoid both gates, in place --
__global__ __launch_bounds__(256) void k_ifg_ln(float* __restrict__ ifg,
                                                const float* __restrict__ g,
                                                const float* __restrict__ bb) {
  size_t m = blockIdx.x;
  float* row = ifg + m * 2048;
  int t = threadIdx.x;
  float4 v0 = ((const float4*)row)[t];
  float4 v1 = ((const float4*)row)[t + 256];
  float lsum = v0.x + v0.y + v0.z + v0.w + v1.x + v1.y + v1.z + v1.w;
  float lss = v0.x * v0.x + v0.y * v0.y + v0.z * v0.z + v0.w * v0.w +
              v1.x * v1.x + v1.y * v1.y + v1.z * v1.z + v1.w * v1.w;
  float mean, var;
  block_stats(lsum, lss, 2048, mean, var);
  float rs = rsqrtf(var + 1e-6f);
  float4 g0 = ((const float4*)g)[t], g1 = ((const float4*)g)[t + 256];
  float4 b0 = ((const float4*)bb)[t], b1 = ((const float4*)bb)[t + 256];
  float4 o0, o1;
  o0.x = sigmoidf_((v0.x - mean) * rs * g0.x + b0.x);
  o0.y = sigmoidf_((v0.y - mean) * rs * g0.y + b0.y);
  o0.z = sigmoidf_((v0.z - mean) * rs * g0.z + b0.z);
  o0.w = sigmoidf_((v0.w - mean) * rs * g0.w + b0.w);
  o1.x = sigmoidf_((v1.x - mean) * rs * g1.x + b1.x);
  o1.y = sigmoidf_((v1.y - mean) * rs * g1.y + b1.y);
  o1.z = sigmoidf_((v1.z - mean) * rs * g1.z + b1.z);
  o1.w = sigmoidf_((v1.w - mean) * rs * g1.w + b1.w);
  ((float4*)row)[t] = o0;
  ((float4*)row)[t + 256] = o1;
}

// ---------------- K6: LN over (H,FH)=4096 + relu, bf16 in place ----------------
__global__ __launch_bounds__(256) void k_hid_ln(__hip_bfloat16* __restrict__ hid,
                                                const float* __restrict__ g,
                                                const float* __restrict__ bb) {
  size_t m = blockIdx.x;
  __hip_bfloat16* row = hid + m * (H * FH);
  int t = threadIdx.x;
  float v[16];
  float lsum = 0.0f, lss = 0.0f;
  #pragma unroll
  for (int i = 0; i < 16; ++i) {
    v[i] = __bfloat162float(row[t * 16 + i]);
    lsum += v[i];
    lss += v[i] * v[i];
  }
  float mean, var;
  block_stats(lsum, lss, H * FH, mean, var);
  float rs = rsqrtf(var + 1e-6f);
  #pragma unroll
  for (int i = 0; i < 16; ++i) {
    int j = t * 16 + i;
    float o = (v[i] - mean) * rs * g[j] + bb[j];
    o = o > 0.0f ? o : 0.0f;
    row[j] = __float2bfloat16(o);
  }
}

// ---------------- K8: sequential scan c = f*c + i ----------------
__global__ void k_scan(const float* __restrict__ ifg, const float* __restrict__ init_cx,
                       float* __restrict__ cell) {
  int bh = blockIdx.x;
  int b = bh / H, h = bh % H;
  int d = threadIdx.x;
  float c = init_cx[h * D + d];
  for (int s = 0; s < S; ++s) {
    size_t mh = (size_t)(b * S + s) * H + h;
    float iv = ifg[(mh * 2 + 0) * D + d];
    float fv = ifg[(mh * 2 + 1) * D + d];
    c = fv * c + iv;
    cell[mh * D + d] = c;
  }
}

// ---------------- K10: og LN over (H,D)=1024, sigmoid, * cell -> out ----------
__global__ __launch_bounds__(256) void k_og_out(const float* __restrict__ og,
                                                const float* __restrict__ cell,
                                                const float* __restrict__ g,
                                                const float* __restrict__ bb,
                                                float* __restrict__ out) {
  size_t m = blockIdx.x;
  const float* row = og + m * (H * D);
  int t = threadIdx.x;
  float4 v = ((const float4*)row)[t];
  float lsum = v.x + v.y + v.z + v.w;
  float lss = v.x * v.x + v.y * v.y + v.z * v.z + v.w * v.w;
  float mean, var;
  block_stats(lsum, lss, H * D, mean, var);
  float rs = rsqrtf(var + 1e-6f);
  float4 gv = ((const float4*)g)[t];
  float4 bv = ((const float4*)bb)[t];
  float4 cv = ((const float4*)(cell + m * (H * D)))[t];
  float4 o;
  o.x = sigmoidf_((v.x - mean) * rs * gv.x + bv.x) * cv.x;
  o.y = sigmoidf_((v.y - mean) * rs * gv.y + bv.y) * cv.y;
  o.z = sigmoidf_((v.z - mean) * rs * gv.z + bv.z) * cv.z;
  o.w = sigmoidf_((v.w - mean) * rs * gv.w + bv.w) * cv.w;
  ((float4*)(out + m * (H * D)))[t] = o;
}

extern "C" void kernel_launch(void* const* d_in, const int* in_sizes, int n_in,
                              void* d_out, int out_size, void* d_ws, size_t ws_size,
                              hipStream_t stream) {
  (void)in_sizes; (void)n_in; (void)out_size; (void)ws_size;
  const float* x       = (const float*)d_in[0];
  const float* W_ifg   = (const float*)d_in[1];
  const float* b_ifg   = (const float*)d_in[2];
  const float* W_hid1  = (const float*)d_in[3];
  const float* b_hid1  = (const float*)d_in[4];
  const float* hid_g   = (const float*)d_in[5];
  const float* hid_b   = (const float*)d_in[6];
  const float* W_hid2  = (const float*)d_in[7];
  const float* b_hid2  = (const float*)d_in[8];
  const float* W_og    = (const float*)d_in[9];
  const float* b_og    = (const float*)d_in[10];
  const float* og_g    = (const float*)d_in[11];
  const float* og_b    = (const float*)d_in[12];
  const float* csum_g  = (const float*)d_in[13];
  const float* csum_b  = (const float*)d_in[14];
  const float* ifg_g   = (const float*)d_in[15];
  const float* ifg_b   = (const float*)d_in[16];
  const float* init_cx = (const float*)d_in[17];
  float* out = (float*)d_out;

  char* w = (char*)d_ws;
  float* P    = (float*)w;                         // 33.5 MB: prefix/csum, later og
  float* ifg  = (float*)(w + 33554432);            // 67 MB: ifg -> gates -> f,i
  float* cell = (float*)(w + 100663296);           // 33.5 MB
  __hip_bfloat16* hid = (__hip_bfloat16*)(w + 134217728);  // 33.5 MB (bf16)

  k_prefix<<<dim3(B * H), dim3(D), 0, stream>>>(x, P);
  k_csum_ln<<<dim3(M), dim3(256), 0, stream>>>(P, csum_g, csum_b);
  k_gemm<256, 256, 0, 0><<<dim3(4, 128, 8), dim3(256), 0, stream>>>(
      x, P, nullptr, W_ifg, b_ifg, ifg, nullptr, nullptr);
  k_gemm<512, 256, 0, 1><<<dim3(8, 128, 8), dim3(256), 0, stream>>>(
      x, P, nullptr, W_hid1, b_hid1, nullptr, hid, nullptr);
  k_ifg_ln<<<dim3(M), dim3(256), 0, stream>>>(ifg, ifg_g, ifg_b);
  k_hid_ln<<<dim3(M), dim3(256), 0, stream>>>(hid, hid_g, hid_b);
  k_gemm<128, 512, 1, 2><<<dim3(2, 128, 8), dim3(256), 0, stream>>>(
      nullptr, nullptr, hid, W_hid2, b_hid2, nullptr, nullptr, ifg);
  k_scan<<<dim3(B * H), dim3(D), 0, stream>>>(ifg, init_cx, cell);
  k_gemm<128, 256, 2, 0><<<dim3(2, 128, 8), dim3(256), 0, stream>>>(
      x, cell, nullptr, W_og, b_og, P, nullptr, nullptr);
  k_og_out<<<dim3(M), dim3(256), 0, stream>>>(P, cell, og_g, og_b, out);
}

// Round 4
// 371.724 us; speedup vs baseline: 2.8811x; 2.8811x over previous
//
#include <hip/hip_runtime.h>
#include <hip/hip_bf16.h>

#define DEV static __device__ __forceinline__

constexpr int B = 4, S = 2048, H = 8, D = 128, FH = 512;
constexpr int M = B * S;   // 8192
constexpr int SC = 64;     // scan/prefix chunk length
constexpr int NCH = S / SC; // 32

typedef __attribute__((ext_vector_type(8))) short short8;
typedef __attribute__((ext_vector_type(4))) float f32x4;

DEV float sigmoidf_(float x) { return 1.0f / (1.0f + __expf(-x)); }
DEV float b2f(unsigned short u) { union { unsigned int i; float f; } x; x.i = (unsigned int)u << 16; return x.f; }
DEV unsigned short f2bu(float f) { __hip_bfloat16 b = __float2bfloat16(f); union { __hip_bfloat16 b; unsigned short u; } x; x.b = b; return x.u; }

// ---------------- weight convert + transpose: W[h][k][n] f32 -> Wt[h][n][k] bf16 --
__global__ void k_wcvt(const float* __restrict__ W, __hip_bfloat16* __restrict__ Wt,
                       int K, int N) {
  __shared__ float t[32][33];
  int h = blockIdx.z;
  int k0 = blockIdx.x * 32, n0 = blockIdx.y * 32;
  int tx = threadIdx.x, ty = threadIdx.y;  // 32 x 8
  #pragma unroll
  for (int r = 0; r < 32; r += 8)
    t[ty + r][tx] = W[((size_t)h * K + k0 + ty + r) * N + n0 + tx];
  __syncthreads();
  #pragma unroll
  for (int r = 0; r < 32; r += 8)
    Wt[((size_t)h * N + n0 + ty + r) * K + k0 + tx] = __float2bfloat16(t[tx][ty + r]);
}

// ---------------- prefix phase 1: per-chunk sums ----------------
__global__ void k_pre1(const float* __restrict__ x, float* __restrict__ chsum) {
  int bh = blockIdx.x, ch = blockIdx.y, d = threadIdx.x;
  int b = bh >> 3, h = bh & 7;
  size_t base = ((size_t)(b * S + ch * SC) * H + h) * D + d;
  float s = 0.0f;
  for (int i = 0; i < SC; ++i) s += x[base + (size_t)i * H * D];
  chsum[((size_t)bh * NCH + ch) * D + d] = s;
}

// ---------------- prefix phase 2: scan chunk sums ----------------
__global__ void k_pre2(const float* __restrict__ chsum, float* __restrict__ choff) {
  int bh = blockIdx.x, d = threadIdx.x;
  float a = 0.0f;
  for (int c = 0; c < NCH; ++c) {
    size_t idx = ((size_t)bh * NCH + c) * D + d;
    choff[idx] = a;
    a += chsum[idx];
  }
}

// ---------------- prefix phase 3: write raw exclusive cumsum (bf16) ----------
__global__ void k_pre3(const float* __restrict__ x, const float* __restrict__ choff,
                       __hip_bfloat16* __restrict__ P) {
  int bh = blockIdx.x, ch = blockIdx.y, d = threadIdx.x;
  int b = bh >> 3, h = bh & 7;
  float acc = choff[((size_t)bh * NCH + ch) * D + d];
  for (int i = 0; i < SC; ++i) {
    size_t mh = ((size_t)b * S + ch * SC + i) * H + h;
    P[mh * D + d] = __float2bfloat16(acc);
    acc += x[mh * D + d];
  }
}

// ---------------- block stats helper (mean/var over n elems), 256 threads -------
DEV void block_stats(float lsum, float lss, int n, float& mean, float& var) {
  #pragma unroll
  for (int o = 32; o > 0; o >>= 1) {
    lsum += __shfl_down(lsum, o);
    lss  += __shfl_down(lss, o);
  }
  __shared__ float wsum[4], wss[4];
  int wid = threadIdx.x >> 6;
  if ((threadIdx.x & 63) == 0) { wsum[wid] = lsum; wss[wid] = lss; }
  __syncthreads();
  float s = 0.0f, q = 0.0f;
  #pragma unroll
  for (int i = 0; i < 4; ++i) { s += wsum[i]; q += wss[i]; }
  mean = s / n;
  var = q / n - mean * mean;
}

// ---------------- csum LN over (H,D)=1024: Pb bf16 -> csum bf16 ----------------
__global__ __launch_bounds__(256) void k_csum_ln(const __hip_bfloat16* __restrict__ P,
                                                 const float* __restrict__ g,
                                                 const float* __restrict__ bb,
                                                 __hip_bfloat16* __restrict__ csum) {
  size_t m = blockIdx.x;
  int t = threadIdx.x;
  ushort4 raw = ((const ushort4*)(P + m * 1024))[t];
  float v0 = b2f(raw.x), v1 = b2f(raw.y), v2 = b2f(raw.z), v3 = b2f(raw.w);
  float lsum = v0 + v1 + v2 + v3;
  float lss = v0 * v0 + v1 * v1 + v2 * v2 + v3 * v3;
  float mean, var;
  block_stats(lsum, lss, 1024, mean, var);
  float rs = rsqrtf(var + 1e-6f);
  float4 gv = *(const float4*)(g + t * 4);
  float4 bv = *(const float4*)(bb + t * 4);
  ushort4 o;
  o.x = f2bu((v0 - mean) * rs * gv.x + bv.x);
  o.y = f2bu((v1 - mean) * rs * gv.y + bv.y);
  o.z = f2bu((v2 - mean) * rs * gv.z + bv.z);
  o.w = f2bu((v3 - mean) * rs * gv.w + bv.w);
  ((ushort4*)((unsigned short*)csum + m * 1024))[t] = o;
}

// ---------------- MFMA bf16 GEMM: C[m,h,n] = A[m,h,:] * Wt[h,n,:] + bias --------
// BM=256, BN=128, BK=32; 512 threads = 8 waves (4x2), wave tile 64x64, 4x4 frags.
// AKIND 0: A bf16 [M][H][K] (Ab).
// AKIND 1: A f32 [Af0 | Af1], each [M][H][128].
// AKIND 2: A [x f32 (k<128) | csum bf16 (k>=128)]: Af0 f32, Ab bf16, stride 128.
// EPI 0: f32 out.  EPI 1: bf16 out.  EPI 2: ifg[igate] *= (acc+bias).
template <int N, int K, int AKIND, int EPI>
__global__ __launch_bounds__(512) void k_mgemm(
    const __hip_bfloat16* __restrict__ Ab,
    const float* __restrict__ Af0, const float* __restrict__ Af1,
    const __hip_bfloat16* __restrict__ Wt, const float* __restrict__ bias,
    float* __restrict__ out_f, __hip_bfloat16* __restrict__ out_b,
    float* __restrict__ ifg) {
  constexpr int BM = 256, BN = 128, BK = 32;
  constexpr int LDA = 40;  // bf16 stride (80B): 2-way-max LDS bank aliasing
  __shared__ __align__(16) short As[BM * LDA];
  __shared__ __align__(16) short Bs[BN * LDA];
  int h = blockIdx.z;
  int m0 = blockIdx.y * BM, n0 = blockIdx.x * BN;
  int tid = threadIdx.x;
  int w = tid >> 6, lane = tid & 63;
  int wr = w >> 1, wc = w & 1;
  int l15 = lane & 15, l4 = lane >> 4;
  f32x4 acc[4][4] = {};
  for (int kt = 0; kt < K; kt += BK) {
    // stage A: 256x32 bf16 = 1024 16B chunks, 2 per thread
    #pragma unroll
    for (int r = 0; r < 2; ++r) {
      int q = tid + r * 512;
      int row = q >> 2, cq = q & 3;
      int kk = kt + cq * 8;
      short8 v;
      if (AKIND == 0) {
        v = *reinterpret_cast<const short8*>(Ab + ((size_t)(m0 + row) * H + h) * K + kk);
      } else if (AKIND == 2 && kk >= D) {
        v = *reinterpret_cast<const short8*>(Ab + ((size_t)(m0 + row) * H + h) * D + (kk - D));
      } else {
        const float* src;
        if (AKIND == 1 && kk >= D) src = Af1 + ((size_t)(m0 + row) * H + h) * D + (kk - D);
        else                       src = Af0 + ((size_t)(m0 + row) * H + h) * D + kk;
        float4 f0 = ((const float4*)src)[0];
        float4 f1 = ((const float4*)src)[1];
        short8 t;
        t[0] = (short)f2bu(f0.x); t[1] = (short)f2bu(f0.y);
        t[2] = (short)f2bu(f0.z); t[3] = (short)f2bu(f0.w);
        t[4] = (short)f2bu(f1.x); t[5] = (short)f2bu(f1.y);
        t[6] = (short)f2bu(f1.z); t[7] = (short)f2bu(f1.w);
        v = t;
      }
      *reinterpret_cast<short8*>(As + row * LDA + cq * 8) = v;
    }
    // stage B: 128x32 bf16 = 512 chunks, 1 per thread
    {
      int row = tid >> 2, cq = tid & 3;
      short8 v = *reinterpret_cast<const short8*>(
          Wt + ((size_t)h * N + n0 + row) * K + kt + cq * 8);
      *reinterpret_cast<short8*>(Bs + row * LDA + cq * 8) = v;
    }
    __syncthreads();
    short8 a[4], bfr[4];
    #pragma unroll
    for (int i = 0; i < 4; ++i)
      a[i] = *reinterpret_cast<const short8*>(As + (wr * 64 + i * 16 + l15) * LDA + l4 * 8);
    #pragma unroll
    for (int j = 0; j < 4; ++j)
      bfr[j] = *reinterpret_cast<const short8*>(Bs + (wc * 64 + j * 16 + l15) * LDA + l4 * 8);
    #pragma unroll
    for (int i = 0; i < 4; ++i)
      #pragma unroll
      for (int j = 0; j < 4; ++j)
        acc[i][j] = __builtin_amdgcn_mfma_f32_16x16x32_bf16(a[i], bfr[j], acc[i][j], 0, 0, 0);
    __syncthreads();
  }
  // epilogue: C row = (lane>>4)*4 + reg, col = lane&15  [m89-verified]
  #pragma unroll
  for (int i = 0; i < 4; ++i) {
    #pragma unroll
    for (int j = 0; j < 4; ++j) {
      #pragma unroll
      for (int r = 0; r < 4; ++r) {
        int mg = m0 + wr * 64 + i * 16 + l4 * 4 + r;
        int o = n0 + wc * 64 + j * 16 + l15;
        float v = acc[i][j][r] + bias[h * N + o];
        size_t mh = (size_t)mg * H + h;
        if (EPI == 0) {
          out_f[mh * N + o] = v;
        } else if (EPI == 1) {
          out_b[mh * N + o] = __float2bfloat16(v);
        } else {
          size_t idx = mh * 256 + o;  // igate slot (o < 128)
          ifg[idx] = ifg[idx] * v;
        }
      }
    }
  }
}

// ---------------- ifg LN over (H,2,D)=2048 + sigmoid both gates, in place -------
__global__ __launch_bounds__(256) void k_ifg_ln(float* __restrict__ ifg,
                                                const float* __restrict__ g,
                                                const float* __restrict__ bb) {
  size_t m = blockIdx.x;
  float* row = ifg + m * 2048;
  int t = threadIdx.x;
  float4 v0 = ((const float4*)row)[t];
  float4 v1 = ((const float4*)row)[t + 256];
  float lsum = v0.x + v0.y + v0.z + v0.w + v1.x + v1.y + v1.z + v1.w;
  float lss = v0.x * v0.x + v0.y * v0.y + v0.z * v0.z + v0.w * v0.w +
              v1.x * v1.x + v1.y * v1.y + v1.z * v1.z + v1.w * v1.w;
  float mean, var;
  block_stats(lsum, lss, 2048, mean, var);
  float rs = rsqrtf(var + 1e-6f);
  float4 g0 = ((const float4*)g)[t], g1 = ((const float4*)g)[t + 256];
  float4 b0 = ((const float4*)bb)[t], b1 = ((const float4*)bb)[t + 256];
  float4 o0, o1;
  o0.x = sigmoidf_((v0.x - mean) * rs * g0.x + b0.x);
  o0.y = sigmoidf_((v0.y - mean) * rs * g0.y + b0.y);
  o0.z = sigmoidf_((v0.z - mean) * rs * g0.z + b0.z);
  o0.w = sigmoidf_((v0.w - mean) * rs * g0.w + b0.w);
  o1.x = sigmoidf_((v1.x - mean) * rs * g1.x + b1.x);
  o1.y = sigmoidf_((v1.y - mean) * rs * g1.y + b1.y);
  o1.z = sigmoidf_((v1.z - mean) * rs * g1.z + b1.z);
  o1.w = sigmoidf_((v1.w - mean) * rs * g1.w + b1.w);
  ((float4*)row)[t] = o0;
  ((float4*)row)[t + 256] = o1;
}

// ---------------- hid LN over (H,FH)=4096 + relu, bf16 in place -----------------
__global__ __launch_bounds__(256) void k_hid_ln(__hip_bfloat16* __restrict__ hid,
                                                const float* __restrict__ g,
                                                const float* __restrict__ bb) {
  size_t m = blockIdx.x;
  unsigned short* row = (unsigned short*)(hid + m * 4096);
  int t = threadIdx.x;
  short8 r0 = ((const short8*)row)[t * 2];
  short8 r1 = ((const short8*)row)[t * 2 + 1];
  float v[16];
  float lsum = 0.0f, lss = 0.0f;
  #pragma unroll
  for (int i = 0; i < 8; ++i) {
    v[i] = b2f((unsigned short)r0[i]);
    v[i + 8] = b2f((unsigned short)r1[i]);
  }
  #pragma unroll
  for (int i = 0; i < 16; ++i) { lsum += v[i]; lss += v[i] * v[i]; }
  float mean, var;
  block_stats(lsum, lss, 4096, mean, var);
  float rs = rsqrtf(var + 1e-6f);
  short8 o0, o1;
  #pragma unroll
  for (int i = 0; i < 16; ++i) {
    int j = t * 16 + i;
    float o = (v[i] - mean) * rs * g[j] + bb[j];
    o = o > 0.0f ? o : 0.0f;
    if (i < 8) o0[i] = (short)f2bu(o); else o1[i - 8] = (short)f2bu(o);
  }
  ((short8*)row)[t * 2] = o0;
  ((short8*)row)[t * 2 + 1] = o1;
}

// ---------------- scan phase 1: per-chunk composed (F, I) ----------------
__global__ void k_scan1(const float* __restrict__ ifg, float* __restrict__ chF,
                        float* __restrict__ chI) {
  int bh = blockIdx.x, ch = blockIdx.y, d = threadIdx.x;
  int b = bh >> 3, h = bh & 7;
  float F = 1.0f, I = 0.0f;
  for (int i = 0; i < SC; ++i) {
    size_t mh = ((size_t)b * S + ch * SC + i) * H + h;
    float iv = ifg[mh * 256 + d];
    float fv = ifg[mh * 256 + 128 + d];
    F *= fv;
    I = fv * I + iv;
  }
  size_t idx = ((size_t)bh * NCH + ch) * D + d;
  chF[idx] = F;
  chI[idx] = I;
}

// ---------------- scan phase 2: chunk-start cells ----------------
__global__ void k_scan2(const float* __restrict__ chF, const float* __restrict__ chI,
                        const float* __restrict__ init_cx, float* __restrict__ cst) {
  int bh = blockIdx.x, d = threadIdx.x;
  int h = bh & 7;
  float c = init_cx[h * D + d];
  for (int ch = 0; ch < NCH; ++ch) {
    size_t idx = ((size_t)bh * NCH + ch) * D + d;
    cst[idx] = c;
    c = chF[idx] * c + chI[idx];
  }
}

// ---------------- scan phase 3: re-scan chunk, write cell ----------------
__global__ void k_scan3(const float* __restrict__ ifg, const float* __restrict__ cst,
                        float* __restrict__ cell) {
  int bh = blockIdx.x, ch = blockIdx.y, d = threadIdx.x;
  int b = bh >> 3, h = bh & 7;
  float c = cst[((size_t)bh * NCH + ch) * D + d];
  for (int i = 0; i < SC; ++i) {
    size_t mh = ((size_t)b * S + ch * SC + i) * H + h;
    c = ifg[mh * 256 + 128 + d] * c + ifg[mh * 256 + d];
    cell[mh * D + d] = c;
  }
}

// ---------------- og LN over (H,D)=1024, sigmoid, * cell -> out ----------------
__global__ __launch_bounds__(256) void k_og_out(const float* __restrict__ og,
                                                const float* __restrict__ cell,
                                                const float* __restrict__ g,
                                                const float* __restrict__ bb,
                                                float* __restrict__ out) {
  size_t m = blockIdx.x;
  const float* row = og + m * 1024;
  int t = threadIdx.x;
  float4 v = ((const float4*)row)[t];
  float lsum = v.x + v.y + v.z + v.w;
  float lss = v.x * v.x + v.y * v.y + v.z * v.z + v.w * v.w;
  float mean, var;
  block_stats(lsum, lss, 1024, mean, var);
  float rs = rsqrtf(var + 1e-6f);
  float4 gv = ((const float4*)g)[t];
  float4 bv = ((const float4*)bb)[t];
  float4 cv = ((const float4*)(cell + m * 1024))[t];
  float4 o;
  o.x = sigmoidf_((v.x - mean) * rs * gv.x + bv.x) * cv.x;
  o.y = sigmoidf_((v.y - mean) * rs * gv.y + bv.y) * cv.y;
  o.z = sigmoidf_((v.z - mean) * rs * gv.z + bv.z) * cv.z;
  o.w = sigmoidf_((v.w - mean) * rs * gv.w + bv.w) * cv.w;
  ((float4*)(out + m * 1024))[t] = o;
}

extern "C" void kernel_launch(void* const* d_in, const int* in_sizes, int n_in,
                              void* d_out, int out_size, void* d_ws, size_t ws_size,
                              hipStream_t stream) {
  (void)in_sizes; (void)n_in; (void)out_size; (void)ws_size;
  const float* x       = (const float*)d_in[0];
  const float* W_ifg   = (const float*)d_in[1];
  const float* b_ifg   = (const float*)d_in[2];
  const float* W_hid1  = (const float*)d_in[3];
  const float* b_hid1  = (const float*)d_in[4];
  const float* hid_g   = (const float*)d_in[5];
  const float* hid_b   = (const float*)d_in[6];
  const float* W_hid2  = (const float*)d_in[7];
  const float* b_hid2  = (const float*)d_in[8];
  const float* W_og    = (const float*)d_in[9];
  const float* b_og    = (const float*)d_in[10];
  const float* og_g    = (const float*)d_in[11];
  const float* og_b    = (const float*)d_in[12];
  const float* csum_g  = (const float*)d_in[13];
  const float* csum_b  = (const float*)d_in[14];
  const float* ifg_g   = (const float*)d_in[15];
  const float* ifg_b   = (const float*)d_in[16];
  const float* init_cx = (const float*)d_in[17];
  float* out = (float*)d_out;

  // ---- workspace map (all sizes in BYTES; peak 151 MiB < 160 MiB proven) ----
  // [0, 64M):      Pb bf16 (16M, steps 2-3)  ->  ifg f32 (64M, steps 4-11)
  //                -> og f32 (32M, steps 12-13)
  // [64M, 128M):   hid bf16 (64M, steps 5-8) ->  cell f32 (32M, steps 11-13)
  // [128M, 144M):  csum bf16 (16M, steps 3-5)
  // [144M, 151M):  wt_ifg(1M) wt_h1(2M) wt_h2(1M) wt_og(.5M) + 5 scan bufs (.5M each)
  char* w = (char*)d_ws;
  __hip_bfloat16* Pb     = (__hip_bfloat16*)w;
  float* ifg             = (float*)w;
  float* og              = (float*)w;
  __hip_bfloat16* hid    = (__hip_bfloat16*)(w + 67108864);
  float* cell            = (float*)(w + 67108864);
  __hip_bfloat16* csum   = (__hip_bfloat16*)(w + 134217728);
  __hip_bfloat16* wt_ifg = (__hip_bfloat16*)(w + 150994944);
  __hip_bfloat16* wt_h1  = (__hip_bfloat16*)(w + 152043520);
  __hip_bfloat16* wt_h2  = (__hip_bfloat16*)(w + 154140672);
  __hip_bfloat16* wt_og  = (__hip_bfloat16*)(w + 155189248);
  float* chsum           = (float*)(w + 155713536);
  float* choff           = (float*)(w + 156237824);
  float* chF             = (float*)(w + 156762112);
  float* chI             = (float*)(w + 157286400);
  float* cst             = (float*)(w + 157810688);

  // 1. one-off weight transpose+bf16
  k_wcvt<<<dim3(8, 8, 8),  dim3(32, 8), 0, stream>>>(W_ifg,  wt_ifg, 256, 256);
  k_wcvt<<<dim3(8, 16, 8), dim3(32, 8), 0, stream>>>(W_hid1, wt_h1,  256, 512);
  k_wcvt<<<dim3(16, 4, 8), dim3(32, 8), 0, stream>>>(W_hid2, wt_h2,  512, 128);
  k_wcvt<<<dim3(8, 4, 8),  dim3(32, 8), 0, stream>>>(W_og,   wt_og,  256, 128);

  // 2-3. chunked exclusive prefix sum -> Pb; LN -> csum
  k_pre1<<<dim3(32, NCH), dim3(D), 0, stream>>>(x, chsum);
  k_pre2<<<dim3(32), dim3(D), 0, stream>>>(chsum, choff);
  k_pre3<<<dim3(32, NCH), dim3(D), 0, stream>>>(x, choff, Pb);
  k_csum_ln<<<dim3(M), dim3(256), 0, stream>>>(Pb, csum_g, csum_b, csum);

  // 4-5. wide GEMMs (A = [x f32 | csum bf16])
  k_mgemm<256, 256, 2, 0><<<dim3(2, 32, 8), dim3(512), 0, stream>>>(
      csum, x, nullptr, wt_ifg, b_ifg, ifg, nullptr, nullptr);
  k_mgemm<512, 256, 2, 1><<<dim3(4, 32, 8), dim3(512), 0, stream>>>(
      csum, x, nullptr, wt_h1, b_hid1, nullptr, hid, nullptr);

  // 6-8. gate LN+sigmoid; hid LN+relu; hidden GEMM fused into igate
  k_ifg_ln<<<dim3(M), dim3(256), 0, stream>>>(ifg, ifg_g, ifg_b);
  k_hid_ln<<<dim3(M), dim3(256), 0, stream>>>(hid, hid_g, hid_b);
  k_mgemm<128, 512, 0, 2><<<dim3(1, 32, 8), dim3(512), 0, stream>>>(
      hid, nullptr, nullptr, wt_h2, b_hid2, nullptr, nullptr, ifg);

  // 9-11. chunked LSTM scan
  k_scan1<<<dim3(32, NCH), dim3(D), 0, stream>>>(ifg, chF, chI);
  k_scan2<<<dim3(32), dim3(D), 0, stream>>>(chF, chI, init_cx, cst);
  k_scan3<<<dim3(32, NCH), dim3(D), 0, stream>>>(ifg, cst, cell);

  // 12-13. og GEMM (A = [x | cell] f32) + final output
  k_mgemm<128, 256, 1, 0><<<dim3(1, 32, 8), dim3(512), 0, stream>>>(
      nullptr, x, cell, wt_og, b_og, og, nullptr, nullptr);
  k_og_out<<<dim3(M), dim3(256), 0, stream>>>(og, cell, og_g, og_b, out);
}